// Round 2
// baseline (507.971 us; speedup 1.0000x reference)
//
#include <hip/hip_runtime.h>
#include <hip/hip_bf16.h>
#include <stdint.h>
#include <stddef.h>

// Problem constants (from reference setup_inputs)
#define N_NODES 8192
#define DIM     256
#define BATCH   4096
#define CLASSES 1000
#define ALPHA_C 1.0f
#define BETA_C  0.01f
#define GAMMA_C 0.1f

typedef __bf16 bf16_t;
typedef __bf16 bf16x8 __attribute__((ext_vector_type(8)));
typedef __bf16 bf16x4 __attribute__((ext_vector_type(4)));
typedef float  f32x4  __attribute__((ext_vector_type(4)));
typedef float  f32x16 __attribute__((ext_vector_type(16)));

// Async global->LDS DMA, 16 B/lane, dest = wave-uniform base + lane*16.
__device__ __forceinline__ void async16(const void* g, void* l) {
  __builtin_amdgcn_global_load_lds(
      (const __attribute__((address_space(1))) uint32_t*)g,
      (__attribute__((address_space(3))) uint32_t*)l, 16, 0, 0);
}

// ---------------------------------------------------------------------------
// Prep: L2-normalize each embedding row (fp32 math) and store bf16 U[N][D].
// ---------------------------------------------------------------------------
__global__ __launch_bounds__(256) void prep_kernel(
    const float* __restrict__ emb, bf16_t* __restrict__ U) {
  const int row = blockIdx.x;
  const int t = threadIdx.x;
  const float v = emb[(size_t)row * DIM + t];
  float sq = v * v;
  for (int off = 32; off; off >>= 1) sq += __shfl_down(sq, off);
  __shared__ float red[4];
  if ((t & 63) == 0) red[t >> 6] = sq;
  __syncthreads();
  const float total = red[0] + red[1] + red[2] + red[3];
  U[(size_t)row * DIM + t] = (bf16_t)(v * rsqrtf(total));
}

// ---------------------------------------------------------------------------
// Transpose U[N][D] -> Ut[D][N] (bf16), 64x64 tiles through LDS.
// ---------------------------------------------------------------------------
__global__ __launch_bounds__(256) void transpose_kernel(
    const bf16_t* __restrict__ U, bf16_t* __restrict__ Ut) {
  __shared__ bf16_t tile[64][72];  // +8 pad: dodge bank conflicts
  const int i0 = blockIdx.x * 64, d0 = blockIdx.y * 64;
  const int t = threadIdx.x;
  const int r = t >> 3, c8 = (t & 7) * 8;
#pragma unroll
  for (int it = 0; it < 2; ++it) {
    const int row = r + it * 32;
    *(bf16x8*)&tile[row][c8] =
        *(const bf16x8*)&U[(size_t)(i0 + row) * DIM + d0 + c8];
  }
  __syncthreads();
#pragma unroll
  for (int it = 0; it < 2; ++it) {
    const int d = r + it * 32;
    bf16x8 v;
#pragma unroll
    for (int j = 0; j < 8; ++j) v[j] = tile[c8 + j][d];
    *(bf16x8*)&Ut[(size_t)(d0 + d) * N_NODES + i0 + c8] = v;
  }
}

// ---------------------------------------------------------------------------
// Cross-entropy: one block per batch row; single global pass, logits in regs.
// ---------------------------------------------------------------------------
__global__ __launch_bounds__(256) void ce_kernel(
    const float* __restrict__ pred, const int* __restrict__ target,
    float* __restrict__ out) {
  const int row = blockIdx.x;
  const int t = threadIdx.x;
  const float* p = pred + (size_t)row * CLASSES;

  float v[4];
  for (int k = 0; k < 4; ++k) {
    const int c = t + k * 256;
    v[k] = (c < CLASSES) ? p[c] : -INFINITY;
  }

  float m = fmaxf(fmaxf(v[0], v[1]), fmaxf(v[2], v[3]));
  for (int off = 32; off; off >>= 1) m = fmaxf(m, __shfl_down(m, off));

  __shared__ float red[8];
  const int wave = t >> 6, lane = t & 63;
  if (lane == 0) red[wave] = m;
  __syncthreads();
  if (t == 0) red[4] = fmaxf(fmaxf(red[0], red[1]), fmaxf(red[2], red[3]));
  __syncthreads();
  const float mx = red[4];

  float s = 0.f;
  for (int k = 0; k < 4; ++k) s += __expf(v[k] - mx);
  for (int off = 32; off; off >>= 1) s += __shfl_down(s, off);
  if (lane == 0) red[wave] = s;
  __syncthreads();
  if (t == 0) {
    float ssum = red[0] + red[1] + red[2] + red[3];
    float lse = mx + __logf(ssum);
    float loss = lse - p[target[row]];
    atomicAdd(out, loss * (ALPHA_C / (float)BATCH));
  }
}

// ---------------------------------------------------------------------------
// Semantic kernel via trace identity:
//   sum_ij a_ij*sim_ij = tr(U^T A U),  tr = sum_i U_i . W_i,  W = A*U
// 2-phase double-buffered pipeline (T3-minimum): STAGE(next buf) issued
// BEFORE compute(cur buf); one __syncthreads per chunk (implicit vmcnt(0)
// drain overlaps the in-flight adj stream with nothing left to do anyway).
// Block: 512 threads (8 waves, 2d x 4i), BN=128 adj rows, BK=64 K-chunk,
// KC=8 K-splits -> grid 64x8 = 512 blocks, 1 block/CU (128 KB LDS).
// Fused exactly-once on wm==0 waves: s_abs (BETA), s_sum (GAMMA*1 term).
// Epilogue: trace from acc x U[i][d]; W never touches HBM.
// ---------------------------------------------------------------------------
#define BN 128
#define BK 64
#define KC 8
#define KW (N_NODES / KC)   // 1024
#define NCHUNK (KW / BK)    // 16

__global__ __launch_bounds__(512, 2) void semantic_kernel(
    const float* __restrict__ adj, const bf16_t* __restrict__ U,
    const bf16_t* __restrict__ Ut, float* __restrict__ out) {
  __shared__ __align__(16) bf16_t lds_ut[2][DIM * BK];  // 2 x 32 KB, swizzled
  __shared__ __align__(16) float  lds_a[2][BN * BK];    // 2 x 32 KB, swizzled
  __shared__ float red[8];

  const int t = threadIdx.x;
  const int w = t >> 6, lane = t & 63;
  const int wm = w >> 2, wn = w & 3;  // wave-M (d half), wave-N (i quarter)
  const int m = lane & 31, h = lane >> 5;
  const int i0 = blockIdx.x * BN;
  const int k0 = blockIdx.y * KW;

  f32x16 acc[4] = {};  // mr: d = wm*128 + mr*32 + C-row-pattern
  float s_abs = 0.f, s_sum = 0.f;

  // Staging lane maps. Ut: 8 lanes/row (8x16B chunks), swizzle c^(r&7).
  const int ut_rl = lane >> 3;
  const int ut_c = (lane & 7) ^ ut_rl;
  // adj: 16 lanes/row (16x16B chunks), swizzle c^(r&15).
  const int a_rl = lane >> 4;

  auto STAGE = [&](int buf, int ck) {
    const int ko = k0 + ck * BK;
    // Ut slab [256][64] bf16 = 32 wave-loads; each wave 4 (8 rows each).
#pragma unroll
    for (int ii = 0; ii < 4; ++ii) {
      const int rbase = ii * 64 + w * 8;  // wave-uniform
      async16(Ut + (size_t)(rbase + ut_rl) * N_NODES + ko + ut_c * 8,
              &lds_ut[buf][rbase * BK]);
    }
    // adj tile [128][64] f32 = 32 wave-loads; each wave 4 (4 rows each).
#pragma unroll
    for (int ii = 0; ii < 4; ++ii) {
      const int rbase = w * 16 + ii * 4;  // wave-uniform
      const int r = rbase + a_rl;
      const int c = (lane & 15) ^ (r & 15);
      async16(adj + (size_t)(i0 + r) * N_NODES + ko + c * 4,
              &lds_a[buf][rbase * BK]);
    }
  };

  STAGE(0, 0);
  __syncthreads();  // drain prologue stage

  int buf = 0;
  for (int ck = 0; ck < NCHUNK; ++ck) {
    if (ck + 1 < NCHUNK) STAGE(buf ^ 1, ck + 1);  // issue next, then compute
#pragma unroll
    for (int kk = 0; kk < 4; ++kk) {
      bf16x8 af[4];
#pragma unroll
      for (int mr = 0; mr < 4; ++mr) {
        const int rd = wm * 128 + mr * 32 + m;
        af[mr] = *(const bf16x8*)
            &lds_ut[buf][rd * BK + (((kk * 2 + h) ^ (rd & 7)) * 8)];
      }
      const int ri = wn * 32 + m;
      const int c0 = kk * 4 + h * 2;  // global 16B chunk: k = kk*16 + h*8
      const f32x4 b0 =
          *(const f32x4*)&lds_a[buf][ri * BK + ((c0 ^ (ri & 15)) * 4)];
      const f32x4 b1 =
          *(const f32x4*)&lds_a[buf][ri * BK + (((c0 + 1) ^ (ri & 15)) * 4)];
      if (wm == 0) {  // each adj element counted exactly once
        s_abs += fabsf(b0[0]) + fabsf(b0[1]) + fabsf(b0[2]) + fabsf(b0[3]) +
                 fabsf(b1[0]) + fabsf(b1[1]) + fabsf(b1[2]) + fabsf(b1[3]);
        s_sum += b0[0] + b0[1] + b0[2] + b0[3] + b1[0] + b1[1] + b1[2] + b1[3];
      }
      bf16x8 bb;
      bb[0] = (bf16_t)b0[0]; bb[1] = (bf16_t)b0[1];
      bb[2] = (bf16_t)b0[2]; bb[3] = (bf16_t)b0[3];
      bb[4] = (bf16_t)b1[0]; bb[5] = (bf16_t)b1[1];
      bb[6] = (bf16_t)b1[2]; bb[7] = (bf16_t)b1[3];
#pragma unroll
      for (int mr = 0; mr < 4; ++mr)
        acc[mr] = __builtin_amdgcn_mfma_f32_32x32x16_bf16(af[mr], bb, acc[mr],
                                                          0, 0, 0);
    }
    __syncthreads();  // drains next-chunk stage (vmcnt) + our lds reads
    buf ^= 1;
  }

  // Trace epilogue: C/D layout col = lane&31 = i-rel, row = (r&3)+8*(r>>2)+4h.
  float tr = 0.f;
  const bf16_t* Urow = U + (size_t)(i0 + wn * 32 + m) * DIM;
#pragma unroll
  for (int mr = 0; mr < 4; ++mr) {
#pragma unroll
    for (int rq = 0; rq < 4; ++rq) {
      const int d = wm * 128 + mr * 32 + rq * 8 + h * 4;
      const bf16x4 uu = *(const bf16x4*)&Urow[d];
      tr += acc[mr][rq * 4 + 0] * (float)uu[0] +
            acc[mr][rq * 4 + 1] * (float)uu[1] +
            acc[mr][rq * 4 + 2] * (float)uu[2] +
            acc[mr][rq * 4 + 3] * (float)uu[3];
    }
  }

  float contrib = -GAMMA_C * tr;
  if (wm == 0) contrib += BETA_C * s_abs + GAMMA_C * s_sum;
  for (int off = 32; off; off >>= 1) contrib += __shfl_down(contrib, off);
  if (lane == 0) red[w] = contrib;
  __syncthreads();
  if (t == 0) {
    float tot = 0.f;
    for (int i = 0; i < 8; ++i) tot += red[i];
    const float inv = 1.f / ((float)N_NODES * (float)N_NODES);
    atomicAdd(out, tot * inv);
  }
}

// ---------------------------------------------------------------------------
extern "C" void kernel_launch(void* const* d_in, const int* in_sizes, int n_in,
                              void* d_out, int out_size, void* d_ws,
                              size_t ws_size, hipStream_t stream) {
  const float* pred   = (const float*)d_in[0];
  const int*   target = (const int*)d_in[1];
  const float* adj    = (const float*)d_in[2];
  const float* emb    = (const float*)d_in[3];
  float* out = (float*)d_out;

  bf16_t* U  = (bf16_t*)d_ws;                   // 4 MB normalized rows [N][D]
  bf16_t* Ut = U + (size_t)N_NODES * DIM;       // 4 MB transposed [D][N]

  hipMemsetAsync(d_out, 0, sizeof(float), stream);
  prep_kernel<<<N_NODES, 256, 0, stream>>>(emb, U);
  transpose_kernel<<<dim3(N_NODES / 64, DIM / 64), 256, 0, stream>>>(U, Ut);
  ce_kernel<<<BATCH, 256, 0, stream>>>(pred, target, out);
  semantic_kernel<<<dim3(N_NODES / BN, KC), 512, 0, stream>>>(adj, U, Ut, out);
}

// Round 3
// 485.254 us; speedup vs baseline: 1.0468x; 1.0468x over previous
//
#include <hip/hip_runtime.h>
#include <hip/hip_bf16.h>
#include <stdint.h>
#include <stddef.h>

// Problem constants (from reference setup_inputs)
#define N_NODES 8192
#define DIM     256
#define BATCH   4096
#define CLASSES 1000
#define ALPHA_C 1.0f
#define BETA_C  0.01f
#define GAMMA_C 0.1f

typedef __bf16 bf16_t;
typedef __bf16 bf16x8 __attribute__((ext_vector_type(8)));
typedef __bf16 bf16x4 __attribute__((ext_vector_type(4)));
typedef float  f32x4  __attribute__((ext_vector_type(4)));
typedef float  f32x16 __attribute__((ext_vector_type(16)));

// Async global->LDS DMA, 16 B/lane, dest = wave-uniform base + lane*16.
__device__ __forceinline__ void async16(const void* g, void* l) {
  __builtin_amdgcn_global_load_lds(
      (const __attribute__((address_space(1))) uint32_t*)g,
      (__attribute__((address_space(3))) uint32_t*)l, 16, 0, 0);
}

// ---------------------------------------------------------------------------
// Prep: L2-normalize each embedding row (fp32 math) and store bf16 U[N][D].
// ---------------------------------------------------------------------------
__global__ __launch_bounds__(256) void prep_kernel(
    const float* __restrict__ emb, bf16_t* __restrict__ U) {
  const int row = blockIdx.x;
  const int t = threadIdx.x;
  const float v = emb[(size_t)row * DIM + t];
  float sq = v * v;
  for (int off = 32; off; off >>= 1) sq += __shfl_down(sq, off);
  __shared__ float red[4];
  if ((t & 63) == 0) red[t >> 6] = sq;
  __syncthreads();
  const float total = red[0] + red[1] + red[2] + red[3];
  U[(size_t)row * DIM + t] = (bf16_t)(v * rsqrtf(total));
}

// ---------------------------------------------------------------------------
// Transpose U[N][D] -> Ut[D][N] (bf16), 64x64 tiles through LDS.
// ---------------------------------------------------------------------------
__global__ __launch_bounds__(256) void transpose_kernel(
    const bf16_t* __restrict__ U, bf16_t* __restrict__ Ut) {
  __shared__ bf16_t tile[64][72];  // +8 pad: dodge bank conflicts
  const int i0 = blockIdx.x * 64, d0 = blockIdx.y * 64;
  const int t = threadIdx.x;
  const int r = t >> 3, c8 = (t & 7) * 8;
#pragma unroll
  for (int it = 0; it < 2; ++it) {
    const int row = r + it * 32;
    *(bf16x8*)&tile[row][c8] =
        *(const bf16x8*)&U[(size_t)(i0 + row) * DIM + d0 + c8];
  }
  __syncthreads();
#pragma unroll
  for (int it = 0; it < 2; ++it) {
    const int d = r + it * 32;
    bf16x8 v;
#pragma unroll
    for (int j = 0; j < 8; ++j) v[j] = tile[c8 + j][d];
    *(bf16x8*)&Ut[(size_t)(d0 + d) * N_NODES + i0 + c8] = v;
  }
}

// ---------------------------------------------------------------------------
// Cross-entropy: one block per batch row; single global pass, logits in regs.
// ---------------------------------------------------------------------------
__global__ __launch_bounds__(256) void ce_kernel(
    const float* __restrict__ pred, const int* __restrict__ target,
    float* __restrict__ out) {
  const int row = blockIdx.x;
  const int t = threadIdx.x;
  const float* p = pred + (size_t)row * CLASSES;

  float v[4];
  for (int k = 0; k < 4; ++k) {
    const int c = t + k * 256;
    v[k] = (c < CLASSES) ? p[c] : -INFINITY;
  }

  float m = fmaxf(fmaxf(v[0], v[1]), fmaxf(v[2], v[3]));
  for (int off = 32; off; off >>= 1) m = fmaxf(m, __shfl_down(m, off));

  __shared__ float red[8];
  const int wave = t >> 6, lane = t & 63;
  if (lane == 0) red[wave] = m;
  __syncthreads();
  if (t == 0) red[4] = fmaxf(fmaxf(red[0], red[1]), fmaxf(red[2], red[3]));
  __syncthreads();
  const float mx = red[4];

  float s = 0.f;
  for (int k = 0; k < 4; ++k) s += __expf(v[k] - mx);
  for (int off = 32; off; off >>= 1) s += __shfl_down(s, off);
  if (lane == 0) red[wave] = s;
  __syncthreads();
  if (t == 0) {
    float ssum = red[0] + red[1] + red[2] + red[3];
    float lse = mx + __logf(ssum);
    float loss = lse - p[target[row]];
    atomicAdd(out, loss * (ALPHA_C / (float)BATCH));
  }
}

// ---------------------------------------------------------------------------
// Semantic kernel via trace identity:
//   sum_ij a_ij*sim_ij = tr(U^T A U),  tr = sum_i U_i . W_i,  W = A*U
// BARRIER-FREE K-loop: the block's whole Ut slab [256 d][256 k] (128 KB)
// is staged ONCE (one barrier), then adj streams DIRECTLY to registers
// with an 8-kstep ring prefetch (static indices -> regs). With no
// per-chunk __syncthreads there is no vmcnt(0) drain: compiler emits
// counted waits before each use, ~16 loads/wave stay in flight -> HBM
// saturates on intra-wave MLP alone (1 block/CU, 8 waves).
// Block: 512 thr (8 waves = 2 wm x 4 wn), BN=128 adj rows, KW=256 K-window.
// Grid 64 x 32: adj read exactly once. s_abs/s_sum fused exactly-once on
// wm==0 waves. Trace folded into the accumulator epilogue; W never in HBM.
// LDS swizzle: pos p of row r holds global 16B-chunk p^(r&31) (32 slots:
// b128 reads at per-quarter structural minimum).
// ---------------------------------------------------------------------------
#define BN 128
#define KW 256
#define KC (N_NODES / KW)   // 32
#define NKS (KW / 16)       // 16 k-steps of 16
#define PF 8                // adj prefetch depth (k-steps)

__global__ __launch_bounds__(512, 2) void semantic_kernel(
    const float* __restrict__ adj, const bf16_t* __restrict__ U,
    const bf16_t* __restrict__ Ut, float* __restrict__ out) {
  __shared__ __align__(16) bf16_t lds_ut[DIM * KW];  // 128 KB, swizzled
  __shared__ float red[8];

  const int t = threadIdx.x;
  const int w = t >> 6, lane = t & 63;
  const int wm = w >> 2, wn = w & 3;  // wave-M (d half), wave-N (i quarter)
  const int m = lane & 31, h = lane >> 5;
  const int i0 = blockIdx.x * BN;
  const int k0 = blockIdx.y * KW;

  f32x16 acc[4] = {};  // mr: d = wm*128 + mr*32 + C-row-pattern
  float s_abs = 0.f, s_sum = 0.f;

  // adj per-lane base: row i = i0 + wn*32 + m, cols k0 + ks*16 + h*8 + 0..7
  const float* ap = adj + (size_t)(i0 + wn * 32 + m) * N_NODES + k0 + h * 8;

  // Prologue: issue first PF ksteps of adj (HBM) BEFORE the Ut stage (L2)
  // so both streams are in flight when the single barrier drains.
  f32x4 pb[PF][2];
#pragma unroll
  for (int ks = 0; ks < PF; ++ks) {
    pb[ks][0] = *(const f32x4*)(ap + ks * 16);
    pb[ks][1] = *(const f32x4*)(ap + ks * 16 + 4);
  }

  // Stage Ut slab once: 128 wave-loads (16 per wave), 2 rows per load.
  {
    const int rl = lane >> 5;  // 0..1
    const int p = lane & 31;   // LDS 16B-chunk position this lane fills
#pragma unroll
    for (int ii = 0; ii < 16; ++ii) {
      const int rbase = w * 32 + ii * 2;  // wave-uniform
      const int r = rbase + rl;
      async16(Ut + (size_t)r * N_NODES + k0 + ((p ^ (r & 31)) * 8),
              &lds_ut[rbase * KW]);
    }
  }
  __syncthreads();  // the ONLY barrier before the epilogue

  // Barrier-free main loop over 16 ksteps (K=16 each).
#pragma unroll
  for (int ks = 0; ks < NKS; ++ks) {
    const int s = ks & (PF - 1);
    const f32x4 b0 = pb[s][0];
    const f32x4 b1 = pb[s][1];
    if (ks + PF < NKS) {  // refill ring slot for kstep ks+PF
      pb[s][0] = *(const f32x4*)(ap + (ks + PF) * 16);
      pb[s][1] = *(const f32x4*)(ap + (ks + PF) * 16 + 4);
    }

    bf16x8 af[4];
#pragma unroll
    for (int mr = 0; mr < 4; ++mr) {
      const int rd = wm * 128 + mr * 32 + m;  // rd&31 == m
      af[mr] = *(const bf16x8*)&lds_ut[rd * KW + (((ks * 2 + h) ^ m) * 8)];
    }

    if (wm == 0) {  // each adj element counted exactly once across grid
      s_abs += fabsf(b0[0]) + fabsf(b0[1]) + fabsf(b0[2]) + fabsf(b0[3]) +
               fabsf(b1[0]) + fabsf(b1[1]) + fabsf(b1[2]) + fabsf(b1[3]);
      s_sum += b0[0] + b0[1] + b0[2] + b0[3] + b1[0] + b1[1] + b1[2] + b1[3];
    }

    bf16x8 bb;
    bb[0] = (bf16_t)b0[0]; bb[1] = (bf16_t)b0[1];
    bb[2] = (bf16_t)b0[2]; bb[3] = (bf16_t)b0[3];
    bb[4] = (bf16_t)b1[0]; bb[5] = (bf16_t)b1[1];
    bb[6] = (bf16_t)b1[2]; bb[7] = (bf16_t)b1[3];
#pragma unroll
    for (int mr = 0; mr < 4; ++mr)
      acc[mr] = __builtin_amdgcn_mfma_f32_32x32x16_bf16(af[mr], bb, acc[mr],
                                                        0, 0, 0);
  }

  // Trace epilogue: C/D layout col = lane&31 = i-rel, row = (r&3)+8*(r>>2)+4h.
  float tr = 0.f;
  const bf16_t* Urow = U + (size_t)(i0 + wn * 32 + m) * DIM;
#pragma unroll
  for (int mr = 0; mr < 4; ++mr) {
#pragma unroll
    for (int rq = 0; rq < 4; ++rq) {
      const int d = wm * 128 + mr * 32 + rq * 8 + h * 4;
      const bf16x4 uu = *(const bf16x4*)&Urow[d];
      tr += acc[mr][rq * 4 + 0] * (float)uu[0] +
            acc[mr][rq * 4 + 1] * (float)uu[1] +
            acc[mr][rq * 4 + 2] * (float)uu[2] +
            acc[mr][rq * 4 + 3] * (float)uu[3];
    }
  }

  float contrib = -GAMMA_C * tr;
  if (wm == 0) contrib += BETA_C * s_abs + GAMMA_C * s_sum;
  for (int off = 32; off; off >>= 1) contrib += __shfl_down(contrib, off);
  if (lane == 0) red[w] = contrib;
  __syncthreads();
  if (t == 0) {
    float tot = 0.f;
    for (int i = 0; i < 8; ++i) tot += red[i];
    const float inv = 1.f / ((float)N_NODES * (float)N_NODES);
    atomicAdd(out, tot * inv);
  }
}

// ---------------------------------------------------------------------------
extern "C" void kernel_launch(void* const* d_in, const int* in_sizes, int n_in,
                              void* d_out, int out_size, void* d_ws,
                              size_t ws_size, hipStream_t stream) {
  const float* pred   = (const float*)d_in[0];
  const int*   target = (const int*)d_in[1];
  const float* adj    = (const float*)d_in[2];
  const float* emb    = (const float*)d_in[3];
  float* out = (float*)d_out;

  bf16_t* U  = (bf16_t*)d_ws;                   // 4 MB normalized rows [N][D]
  bf16_t* Ut = U + (size_t)N_NODES * DIM;       // 4 MB transposed [D][N]

  hipMemsetAsync(d_out, 0, sizeof(float), stream);
  prep_kernel<<<N_NODES, 256, 0, stream>>>(emb, U);
  transpose_kernel<<<dim3(N_NODES / 64, DIM / 64), 256, 0, stream>>>(U, Ut);
  ce_kernel<<<BATCH, 256, 0, stream>>>(pred, target, out);
  semantic_kernel<<<dim3(N_NODES / BN, KC), 512, 0, stream>>>(adj, U, Ut, out);
}

// Round 4
// 444.993 us; speedup vs baseline: 1.1415x; 1.0905x over previous
//
#include <hip/hip_runtime.h>
#include <hip/hip_bf16.h>
#include <stdint.h>
#include <stddef.h>

// Problem constants (from reference setup_inputs)
#define N_NODES 8192
#define DIM     256
#define BATCH   4096
#define CLASSES 1000
#define ALPHA_C 1.0f
#define BETA_C  0.01f
#define GAMMA_C 0.1f

typedef __bf16 bf16_t;
typedef __bf16 bf16x8 __attribute__((ext_vector_type(8)));
typedef __bf16 bf16x4 __attribute__((ext_vector_type(4)));
typedef float  f32x4  __attribute__((ext_vector_type(4)));
typedef float  f32x16 __attribute__((ext_vector_type(16)));

// ---------------------------------------------------------------------------
// Prep: L2-normalize each embedding row (fp32 math) and store bf16 U[N][D].
// ---------------------------------------------------------------------------
__global__ __launch_bounds__(256) void prep_kernel(
    const float* __restrict__ emb, bf16_t* __restrict__ U) {
  const int row = blockIdx.x;
  const int t = threadIdx.x;
  const float v = emb[(size_t)row * DIM + t];
  float sq = v * v;
  for (int off = 32; off; off >>= 1) sq += __shfl_down(sq, off);
  __shared__ float red[4];
  if ((t & 63) == 0) red[t >> 6] = sq;
  __syncthreads();
  const float total = red[0] + red[1] + red[2] + red[3];
  U[(size_t)row * DIM + t] = (bf16_t)(v * rsqrtf(total));
}

// ---------------------------------------------------------------------------
// Transpose U[N][D] -> Ut[D][N] (bf16), 64x64 tiles through LDS.
// ---------------------------------------------------------------------------
__global__ __launch_bounds__(256) void transpose_kernel(
    const bf16_t* __restrict__ U, bf16_t* __restrict__ Ut) {
  __shared__ bf16_t tile[64][72];  // +8 pad: dodge bank conflicts
  const int i0 = blockIdx.x * 64, d0 = blockIdx.y * 64;
  const int t = threadIdx.x;
  const int r = t >> 3, c8 = (t & 7) * 8;
#pragma unroll
  for (int it = 0; it < 2; ++it) {
    const int row = r + it * 32;
    *(bf16x8*)&tile[row][c8] =
        *(const bf16x8*)&U[(size_t)(i0 + row) * DIM + d0 + c8];
  }
  __syncthreads();
#pragma unroll
  for (int it = 0; it < 2; ++it) {
    const int d = r + it * 32;
    bf16x8 v;
#pragma unroll
    for (int j = 0; j < 8; ++j) v[j] = tile[c8 + j][d];
    *(bf16x8*)&Ut[(size_t)(d0 + d) * N_NODES + i0 + c8] = v;
  }
}

// ---------------------------------------------------------------------------
// Cross-entropy: one block per batch row; single global pass, logits in regs.
// ---------------------------------------------------------------------------
__global__ __launch_bounds__(256) void ce_kernel(
    const float* __restrict__ pred, const int* __restrict__ target,
    float* __restrict__ out) {
  const int row = blockIdx.x;
  const int t = threadIdx.x;
  const float* p = pred + (size_t)row * CLASSES;

  float v[4];
  for (int k = 0; k < 4; ++k) {
    const int c = t + k * 256;
    v[k] = (c < CLASSES) ? p[c] : -INFINITY;
  }

  float m = fmaxf(fmaxf(v[0], v[1]), fmaxf(v[2], v[3]));
  for (int off = 32; off; off >>= 1) m = fmaxf(m, __shfl_down(m, off));

  __shared__ float red[8];
  const int wave = t >> 6, lane = t & 63;
  if (lane == 0) red[wave] = m;
  __syncthreads();
  if (t == 0) red[4] = fmaxf(fmaxf(red[0], red[1]), fmaxf(red[2], red[3]));
  __syncthreads();
  const float mx = red[4];

  float s = 0.f;
  for (int k = 0; k < 4; ++k) s += __expf(v[k] - mx);
  for (int off = 32; off; off >>= 1) s += __shfl_down(s, off);
  if (lane == 0) red[wave] = s;
  __syncthreads();
  if (t == 0) {
    float ssum = red[0] + red[1] + red[2] + red[3];
    float lse = mx + __logf(ssum);
    float loss = lse - p[target[row]];
    atomicAdd(out, loss * (ALPHA_C / (float)BATCH));
  }
}

// ---------------------------------------------------------------------------
// Semantic kernel via trace identity:
//   sum_ij a_ij*sim_ij = tr(U^T A U),  tr = sum_i U_i . W_i,  W = A*U
// r4: COALESCED DRAM access. All prior variants read adj as multi-row
// gathers (64 lanes x 32 rows x 64 B) -> random-64B DRAM regime capped at
// ~3-4 TB/s delivered. Now: reg-staged coalesced loads (2 rows x 512 B
// contiguous per wave-instr; each block walks a 128-row x 8 KB panel
// sequentially), f32->bf16 convert + |a|/sum(a) fused at staging, LDS
// holds bf16 tiles with PADDED stride SP=136 (17 x 16B slots, odd -> frag
// reads/writes conflict-free). T14 pipeline: issue chunk c+1 loads ->
// compute chunk c -> barrier (vmcnt(0) drain lands after ~2us of compute)
// -> convert+ds_write c+1 -> barrier.
// Block: 512 thr (8 waves = 2 wm x 4 wn), BN=128 rows, BK=128 cols/chunk,
// KW=2048 window -> grid 64 x 4 = 256 blocks = 1/CU, single round.
// Epilogue: trace from acc x U[i][d]; W never touches HBM.
// ---------------------------------------------------------------------------
#define BN 128
#define BK 128
#define KW 2048
#define NCH (KW / BK)   // 16 chunks
#define SP  (BK + 8)    // 136 bf16 = 272 B row stride (odd multiple of 16 B)

__global__ __launch_bounds__(512, 2) void semantic_kernel(
    const float* __restrict__ adj, const bf16_t* __restrict__ U,
    const bf16_t* __restrict__ Ut, float* __restrict__ out) {
  __shared__ __align__(16) bf16_t a_lds[BN * SP];    // 34 KB adj tile (bf16)
  __shared__ __align__(16) bf16_t ut_lds[DIM * SP];  // 68 KB Ut tile
  __shared__ float red[8];

  const int t = threadIdx.x;
  const int w = t >> 6, lane = t & 63;
  const int wm = w >> 2, wn = w & 3;  // wave-M (d half), wave-N (i quarter)
  const int m = lane & 31, h = lane >> 5;
  const int i0 = blockIdx.x * BN;
  const int k0 = blockIdx.y * KW;

  f32x16 acc[4] = {};  // mr: d = wm*128 + mr*32 + C-row-pattern
  float s_abs = 0.f, s_sum = 0.f;

  // Coalesced staging maps.
  // adj: 2 rows per instr (half-wave each, 512 B contiguous per row).
  const int arow0 = w * 16 + (lane >> 5);  // + j*2, j=0..7 -> rows 0..127
  const int acol = (lane & 31) * 4;        // f32 col (also bf16 col in LDS)
  // Ut: 4 rows per instr (16 lanes each, 256 B contiguous per row).
  const int urow0 = w * 32 + (lane >> 4);  // + j*4, j=0..7 -> rows 0..255
  const int ucol = (lane & 15) * 8;        // bf16 col

  f32x4 adjs[8];
  bf16x8 uts[8];

  auto LOADC = [&](int c) {  // issue-early: global -> regs
    const size_t kb = (size_t)k0 + (size_t)c * BK;
#pragma unroll
    for (int j = 0; j < 8; ++j)
      adjs[j] = *(const f32x4*)
          &adj[(size_t)(i0 + arow0 + j * 2) * N_NODES + kb + acol];
#pragma unroll
    for (int j = 0; j < 8; ++j)
      uts[j] = *(const bf16x8*)
          &Ut[(size_t)(urow0 + j * 4) * N_NODES + kb + ucol];
  };

  auto WRITEC = [&]() {  // write-late: convert + fused abs/sum + LDS
#pragma unroll
    for (int j = 0; j < 8; ++j) {
      const f32x4 v = adjs[j];
      s_abs += fabsf(v[0]) + fabsf(v[1]) + fabsf(v[2]) + fabsf(v[3]);
      s_sum += v[0] + v[1] + v[2] + v[3];
      bf16x4 b;
      b[0] = (bf16_t)v[0]; b[1] = (bf16_t)v[1];
      b[2] = (bf16_t)v[2]; b[3] = (bf16_t)v[3];
      *(bf16x4*)&a_lds[(arow0 + j * 2) * SP + acol] = b;
    }
#pragma unroll
    for (int j = 0; j < 8; ++j)
      *(bf16x8*)&ut_lds[(urow0 + j * 4) * SP + ucol] = uts[j];
  };

  LOADC(0);
  WRITEC();
  __syncthreads();

  for (int c = 0; c < NCH; ++c) {
    if (c + 1 < NCH) LOADC(c + 1);  // fly under the compute below
#pragma unroll
    for (int ks = 0; ks < 8; ++ks) {  // BK=128 -> 8 ksteps of K=16
      bf16x8 af[4];
#pragma unroll
      for (int mr = 0; mr < 4; ++mr)
        af[mr] = *(const bf16x8*)
            &ut_lds[(wm * 128 + mr * 32 + m) * SP + ks * 16 + h * 8];
      const bf16x8 bfr = *(const bf16x8*)
          &a_lds[(wn * 32 + m) * SP + ks * 16 + h * 8];
#pragma unroll
      for (int mr = 0; mr < 4; ++mr)
        acc[mr] = __builtin_amdgcn_mfma_f32_32x32x16_bf16(af[mr], bfr,
                                                          acc[mr], 0, 0, 0);
    }
    __syncthreads();  // all lds reads done; drains c+1 loads (post-compute)
    if (c + 1 < NCH) WRITEC();
    __syncthreads();  // c+1 tiles visible
  }

  // Trace epilogue: C/D layout col = lane&31 = i-rel, row = (r&3)+8*(r>>2)+4h.
  float tr = 0.f;
  const bf16_t* Urow = U + (size_t)(i0 + wn * 32 + m) * DIM;
#pragma unroll
  for (int mr = 0; mr < 4; ++mr) {
#pragma unroll
    for (int rq = 0; rq < 4; ++rq) {
      const int d = wm * 128 + mr * 32 + rq * 8 + h * 4;
      const bf16x4 uu = *(const bf16x4*)&Urow[d];
      tr += acc[mr][rq * 4 + 0] * (float)uu[0] +
            acc[mr][rq * 4 + 1] * (float)uu[1] +
            acc[mr][rq * 4 + 2] * (float)uu[2] +
            acc[mr][rq * 4 + 3] * (float)uu[3];
    }
  }

  float contrib = BETA_C * s_abs + GAMMA_C * s_sum - GAMMA_C * tr;
  for (int off = 32; off; off >>= 1) contrib += __shfl_down(contrib, off);
  if (lane == 0) red[w] = contrib;
  __syncthreads();
  if (t == 0) {
    float tot = 0.f;
    for (int i = 0; i < 8; ++i) tot += red[i];
    const float inv = 1.f / ((float)N_NODES * (float)N_NODES);
    atomicAdd(out, tot * inv);
  }
}

// ---------------------------------------------------------------------------
extern "C" void kernel_launch(void* const* d_in, const int* in_sizes, int n_in,
                              void* d_out, int out_size, void* d_ws,
                              size_t ws_size, hipStream_t stream) {
  const float* pred   = (const float*)d_in[0];
  const int*   target = (const int*)d_in[1];
  const float* adj    = (const float*)d_in[2];
  const float* emb    = (const float*)d_in[3];
  float* out = (float*)d_out;

  bf16_t* U  = (bf16_t*)d_ws;                   // 4 MB normalized rows [N][D]
  bf16_t* Ut = U + (size_t)N_NODES * DIM;       // 4 MB transposed [D][N]

  hipMemsetAsync(d_out, 0, sizeof(float), stream);
  prep_kernel<<<N_NODES, 256, 0, stream>>>(emb, U);
  transpose_kernel<<<dim3(N_NODES / 64, DIM / 64), 256, 0, stream>>>(U, Ut);
  ce_kernel<<<BATCH, 256, 0, stream>>>(pred, target, out);
  semantic_kernel<<<dim3(N_NODES / BN, KW == N_NODES ? 1 : N_NODES / KW), 512,
                    0, stream>>>(adj, U, Ut, out);
}